// Round 5
// baseline (775.622 us; speedup 1.0000x reference)
//
#include <hip/hip_runtime.h>
#include <float.h>

#define N_ROWS 65536
#define D_IN   128
#define DH     64
#define K_CB   2048

typedef const __attribute__((address_space(1))) void* gas_p;
typedef __attribute__((address_space(3))) void* las_p;
typedef __bf16 bf16x8 __attribute__((ext_vector_type(8)));
typedef float  f32x4  __attribute__((ext_vector_type(4)));

// ---------------- K1: project 128 -> 64, emit 3-plane bf16 split -----------
// z = zh + zm + zl exactly; rows stored [n][64] with 16B-chunk XOR swizzle
// (chunk c at c ^ (n&7)) so MFMA frag ds_reads are balanced after a LINEAR
// global_load_lds copy. blocks 0..4095: z rows; 4096..4223: emb rows + e2.
__global__ __launch_bounds__(256) void k_project(
    const float* __restrict__ Z, const float* __restrict__ emb,
    const float* __restrict__ W, const float* __restrict__ b,
    __bf16* __restrict__ zpl,   // [3][N_ROWS][64]
    __bf16* __restrict__ epl,   // [3][K_CB][64]
    float* __restrict__ e2) {
  __shared__ __align__(16) float Wl[64 * 140];
  __shared__ __align__(16) float Zl[16 * 128];
  int tid = threadIdx.x;
  const float* src; __bf16* dst; int n0; bool do_e2; size_t plane;
  if ((int)blockIdx.x < 4096) {
    src = Z;   dst = zpl; n0 = blockIdx.x * 16;          do_e2 = false; plane = (size_t)N_ROWS * 64;
  } else {
    src = emb; dst = epl; n0 = (blockIdx.x - 4096) * 16; do_e2 = true;  plane = (size_t)K_CB * 64;
  }

#pragma unroll
  for (int i = 0; i < 8; ++i) {
    int idx4 = tid + 256 * i;
    int j = idx4 >> 5;
    int d4 = (idx4 & 31) * 4;
    *(float4*)&Wl[j * 140 + d4] = *(const float4*)(W + j * 128 + d4);
  }
#pragma unroll
  for (int i = 0; i < 2; ++i) {
    int idx4 = tid + 256 * i;
    int r = idx4 >> 5;
    int d4 = (idx4 & 31) * 4;
    *(float4*)&Zl[r * 128 + d4] = *(const float4*)(src + (size_t)(n0 + r) * 128 + d4);
  }
  int j = tid & 63, g = tid >> 6;
  float bj = b[j];
  __syncthreads();

  float acc[4] = {0.f, 0.f, 0.f, 0.f};
  for (int d4 = 0; d4 < 128; d4 += 4) {
    float4 w4 = *(float4*)&Wl[j * 140 + d4];
#pragma unroll
    for (int i = 0; i < 4; ++i) {
      float4 z4 = *(float4*)&Zl[(g * 4 + i) * 128 + d4];
      acc[i] = fmaf(z4.x, w4.x, fmaf(z4.y, w4.y, fmaf(z4.z, w4.z, fmaf(z4.w, w4.w, acc[i]))));
    }
  }
#pragma unroll
  for (int i = 0; i < 4; ++i) {
    int n = n0 + g * 4 + i;
    float v = acc[i] + bj;
    __bf16 h = (__bf16)v;  float rm = v - (float)h;
    __bf16 m = (__bf16)rm; float rl = rm - (float)m;
    __bf16 l = (__bf16)rl;
    int pos = (((j >> 3) ^ (n & 7)) << 3) | (j & 7);
    size_t base = (size_t)n * 64 + pos;
    dst[base]             = h;
    dst[plane + base]     = m;
    dst[2 * plane + base] = l;
    if (do_e2) {
      float s = v * v;
#pragma unroll
      for (int off = 32; off > 0; off >>= 1) s += __shfl_xor(s, off, 64);
      if (j == 0) e2[n] = s;
    }
  }
}

// ---------------- K2: MFMA score, A-in-regs, Es double-buffered ------------
// 64 z-rows/block, K-tile 64, ONE barrier per tile; wave w covers cols
// w*16..w*16+15 of each tile. 6 bf16 MFMA passes == fp32-accurate dots.
__global__ __launch_bounds__(256, 2) void k_score(
    const __bf16* __restrict__ zpl,    // [3][N_ROWS][64] swizzled
    const __bf16* __restrict__ epl,    // [3][K_CB][64] swizzled
    const float* __restrict__ e2,      // [2048]
    const float* __restrict__ emb,     // [2048][128]
    float* __restrict__ outQ,
    float* __restrict__ outOH,         // null => fallback (write cidx_g)
    int* __restrict__ cidx_g) {
  __shared__ __align__(16) __bf16 Es[2][3 * 64 * 64];   // 2 x 24 KB (planes @ 4096)
  __shared__ __align__(16) __bf16 Zs[3 * 64 * 64];      // 24 KB, prologue only
  __shared__ int cidxs[64];

  int tid = threadIdx.x, lane = tid & 63, wid = tid >> 6;
  int quad = lane >> 4, l16 = lane & 15;
  int colw = wid * 16 + l16;           // this thread's column class within a tile
  int row0 = blockIdx.x * 64;

  // prologue: stage Zs (3x8KB) and Es[0] (tile kt=0), linear 1KB copies
  for (int q = wid; q < 24; q += 4) {
    int p = q >> 3, within = (q & 7) * 1024;
    const char* g = (const char*)zpl + (size_t)p * ((size_t)N_ROWS * 128)
                  + (size_t)row0 * 128 + within + lane * 16;
    __builtin_amdgcn_global_load_lds((gas_p)g, (las_p)((char*)Zs + p * 8192 + within), 16, 0, 0);
  }
  for (int q = wid; q < 24; q += 4) {
    int p = q >> 3, within = (q & 7) * 1024;
    const char* g = (const char*)epl + (size_t)p * (K_CB * 128) + within + lane * 16;
    __builtin_amdgcn_global_load_lds((gas_p)g, (las_p)((char*)Es[0] + p * 8192 + within), 16, 0, 0);
  }
  __syncthreads();                     // drains all prologue loads

  // hoist A fragments: 24 x b128, read ONCE (loop-invariant across kt)
  bf16x8 A[2][4][3];
#pragma unroll
  for (int step = 0; step < 2; ++step)
#pragma unroll
    for (int mt = 0; mt < 4; ++mt) {
      int tr = mt * 16 + l16;
      int cph = (step * 4 + quad) ^ (l16 & 7);
      const __bf16* pa = Zs + tr * 64 + cph * 8;
      A[step][mt][0] = *(const bf16x8*)pa;
      A[step][mt][1] = *(const bf16x8*)(pa + 4096);
      A[step][mt][2] = *(const bf16x8*)(pa + 8192);
    }

  float best[16]; int bidx[16];
#pragma unroll
  for (int s = 0; s < 16; ++s) { best[s] = FLT_MAX; bidx[s] = 0; }

  for (int t = 0; t < 32; ++t) {
    int kt = t * 64;
    if (t > 0) __syncthreads();        // drains tile-t loads (issued at t-1) + old stores
    if (t + 1 < 32) {                  // issue tile t+1 into the other buffer NOW
      __bf16* dbuf = Es[(t + 1) & 1];
      for (int q = wid; q < 24; q += 4) {
        int p = q >> 3, within = (q & 7) * 1024;
        const char* g = (const char*)epl + (size_t)p * (K_CB * 128)
                      + (size_t)(kt + 64) * 128 + within + lane * 16;
        __builtin_amdgcn_global_load_lds((gas_p)g, (las_p)((char*)dbuf + p * 8192 + within), 16, 0, 0);
      }
    }
    if (outOH) {                       // zero-stores flow during compute (write floor)
      float4 zz = make_float4(0.f, 0.f, 0.f, 0.f);
#pragma unroll
      for (int i = 0; i < 4; ++i) {
        int idx = tid * 4 + i;         // 0..1023 float4s: 64 rows x 16 float4
        int r = idx >> 4, c4 = (idx & 15) * 4;
        *(float4*)(outOH + (size_t)(row0 + r) * K_CB + kt + c4) = zz;
      }
    }
    float ev = e2[kt + colw];          // L1/L2-hot after first generation

    const __bf16* base = Es[t & 1];
    f32x4 acc[4];
#pragma unroll
    for (int mt = 0; mt < 4; ++mt) acc[mt] = (f32x4){0.f, 0.f, 0.f, 0.f};

#pragma unroll
    for (int step = 0; step < 2; ++step) {
      int cph = (step * 4 + quad) ^ (l16 & 7);
      const __bf16* pb = base + colw * 64 + cph * 8;
      bf16x8 Bh = *(const bf16x8*)pb;
      bf16x8 Bm = *(const bf16x8*)(pb + 4096);
      bf16x8 Bl = *(const bf16x8*)(pb + 8192);
#pragma unroll
      for (int mt = 0; mt < 4; ++mt) {
        f32x4 c = acc[mt];
        c = __builtin_amdgcn_mfma_f32_16x16x32_bf16(A[step][mt][2], Bh, c, 0, 0, 0); // lh
        c = __builtin_amdgcn_mfma_f32_16x16x32_bf16(A[step][mt][0], Bl, c, 0, 0, 0); // hl
        c = __builtin_amdgcn_mfma_f32_16x16x32_bf16(A[step][mt][1], Bm, c, 0, 0, 0); // mm
        c = __builtin_amdgcn_mfma_f32_16x16x32_bf16(A[step][mt][1], Bh, c, 0, 0, 0); // mh
        c = __builtin_amdgcn_mfma_f32_16x16x32_bf16(A[step][mt][0], Bm, c, 0, 0, 0); // hm
        c = __builtin_amdgcn_mfma_f32_16x16x32_bf16(A[step][mt][0], Bh, c, 0, 0, 0); // hh
        acc[mt] = c;
      }
    }

    int col = kt + colw;               // ascending kt + strict < => earliest index
#pragma unroll
    for (int mt = 0; mt < 4; ++mt)
#pragma unroll
      for (int r = 0; r < 4; ++r) {
        float s = fmaf(-2.0f, acc[mt][r], ev);
        int slot = mt * 4 + r;
        if (s < best[slot]) { best[slot] = s; bidx[slot] = col; }
      }
  }

  // 2-stage argmin reduce: 64 col-classes per row, conflict-free layouts
  __syncthreads();
  float* redm = (float*)Es;                    // [64 slots][65]
  int*   redi = (int*)(redm + 64 * 65);        // [64 slots][65]
#pragma unroll
  for (int mt = 0; mt < 4; ++mt)
#pragma unroll
    for (int r = 0; r < 4; ++r) {
      int row = mt * 16 + quad * 4 + r;        // C-layout: row = quad*4 + reg
      redm[colw * 65 + row] = best[mt * 4 + r];
      redi[colw * 65 + row] = bidx[mt * 4 + r];
    }
  __syncthreads();
  float* rm2 = (float*)Zs;                     // [64][4]
  int*   ri2 = (int*)(rm2 + 256);
  {
    int row = tid & 63, qq = tid >> 6;         // each thread reduces 16 slots
    float m = redm[(qq * 16) * 65 + row]; int mi = redi[(qq * 16) * 65 + row];
#pragma unroll
    for (int s = 1; s < 16; ++s) {
      float v = redm[(qq * 16 + s) * 65 + row]; int vi = redi[(qq * 16 + s) * 65 + row];
      if (v < m || (v == m && vi < mi)) { m = v; mi = vi; }
    }
    rm2[row * 4 + qq] = m; ri2[row * 4 + qq] = mi;
  }
  __syncthreads();
  if (tid < 64) {
    float m = rm2[tid * 4]; int mi = ri2[tid * 4];
#pragma unroll
    for (int s = 1; s < 4; ++s) {
      float v = rm2[tid * 4 + s]; int vi = ri2[tid * 4 + s];
      if (v < m || (v == m && vi < mi)) { m = v; mi = vi; }
    }
    cidxs[tid] = mi;
  }
  __syncthreads();                     // vmcnt(0) drained: all zeros landed

  if (outOH) {
    if (tid < 64) outOH[(size_t)(row0 + tid) * K_CB + cidxs[tid]] = 1.0f;
  } else {
    if (tid < 64) cidx_g[row0 + tid] = cidxs[tid];
  }

  // quantized gather (emb is L2-hot, 1 MB)
#pragma unroll
  for (int i = 0; i < 8; ++i) {
    int idx = tid + 256 * i;
    int r = idx >> 5, c = (idx & 31) * 4;
    *(float4*)(outQ + (size_t)(row0 + r) * D_IN + c) =
        *(const float4*)(emb + (size_t)cidxs[r] * D_IN + c);
  }
}

// ---------------- K3: fallback epilogue (zero one_hot + scatter) -----------
__global__ void k_epilogue(const int* __restrict__ cidx_g, float* __restrict__ outOH) {
  int tid  = threadIdx.x;
  int row0 = blockIdx.x * 64;
  float4 zz4 = make_float4(0.f, 0.f, 0.f, 0.f);
  for (int r = 0; r < 64; ++r) {
    float4* dst = (float4*)(outOH + (size_t)(row0 + r) * K_CB);
    dst[tid]       = zz4;
    dst[tid + 256] = zz4;
  }
  __syncthreads();
  if (tid < 64) {
    int r = row0 + tid;
    outOH[(size_t)r * K_CB + cidx_g[r]] = 1.0f;
  }
}

extern "C" void kernel_launch(void* const* d_in, const int* in_sizes, int n_in,
                              void* d_out, int out_size, void* d_ws, size_t ws_size,
                              hipStream_t stream) {
  (void)in_sizes; (void)n_in; (void)out_size;
  const float* Z   = (const float*)d_in[0];
  const float* W   = (const float*)d_in[1];
  const float* b   = (const float*)d_in[2];
  const float* emb = (const float*)d_in[3];
  float* outQ  = (float*)d_out;
  float* outOH = (float*)d_out + (size_t)N_ROWS * D_IN;

  // ws layout (bytes): epl 786432 | e2 8192 | (zpl 25165824  OR  cidx 262144)
  char* wsb = (char*)d_ws;
  __bf16* epl = (__bf16*)wsb;
  float*  e2  = (float*)(wsb + 786432);
  const size_t need_primary = 786432 + 8192 + (size_t)3 * N_ROWS * 64 * 2;

  if (ws_size >= need_primary) {
    __bf16* zpl = (__bf16*)(wsb + 794624);
    k_project<<<4224, 256, 0, stream>>>(Z, emb, W, b, zpl, epl, e2);
    k_score<<<1024, 256, 0, stream>>>(zpl, epl, e2, emb, outQ, outOH, nullptr);
  } else {
    int*    cidx_g = (int*)(wsb + 794624);
    __bf16* zpl    = (__bf16*)outOH;   // one_hot region doubles as scratch
    k_project<<<4224, 256, 0, stream>>>(Z, emb, W, b, zpl, epl, e2);
    k_score<<<1024, 256, 0, stream>>>(zpl, epl, e2, emb, outQ, nullptr, cidx_g);
    k_epilogue<<<1024, 256, 0, stream>>>(cidx_g, outOH);
  }
}

// Round 6
// 756.643 us; speedup vs baseline: 1.0251x; 1.0251x over previous
//
#include <hip/hip_runtime.h>
#include <float.h>

#define N_ROWS 65536
#define D_IN   128
#define DH     64
#define K_CB   2048

typedef const __attribute__((address_space(1))) void* gas_p;
typedef __attribute__((address_space(3))) void* las_p;
typedef __bf16 bf16x8 __attribute__((ext_vector_type(8)));
typedef float  f32x4  __attribute__((ext_vector_type(4)));

// ---------------- K0: zero the one_hot region (pure write-bound) -----------
__global__ __launch_bounds__(256) void k_zero(float4* __restrict__ p) {
  size_t base = (size_t)blockIdx.x * 4096 + threadIdx.x;   // 64 KB per block
  float4 zz = make_float4(0.f, 0.f, 0.f, 0.f);
#pragma unroll
  for (int j = 0; j < 16; ++j) p[base + 256 * j] = zz;
}

// ---------------- K1: project 128 -> 64, emit 3-plane bf16 split -----------
// z = zh + zm + zl exactly; rows stored [n][64] with 16B-chunk XOR swizzle
// (chunk c at c ^ (n&7)): MFMA frag ds_reads balanced after a LINEAR
// global_load_lds copy. blocks 0..4095: z rows; 4096..4223: emb rows + e2.
__global__ __launch_bounds__(256) void k_project(
    const float* __restrict__ Z, const float* __restrict__ emb,
    const float* __restrict__ W, const float* __restrict__ b,
    __bf16* __restrict__ zpl,   // [3][N_ROWS][64]
    __bf16* __restrict__ epl,   // [3][K_CB][64]
    float* __restrict__ e2) {
  __shared__ __align__(16) float Wl[64 * 140];
  __shared__ __align__(16) float Zl[16 * 128];
  int tid = threadIdx.x;
  const float* src; __bf16* dst; int n0; bool do_e2; size_t plane;
  if ((int)blockIdx.x < 4096) {
    src = Z;   dst = zpl; n0 = blockIdx.x * 16;          do_e2 = false; plane = (size_t)N_ROWS * 64;
  } else {
    src = emb; dst = epl; n0 = (blockIdx.x - 4096) * 16; do_e2 = true;  plane = (size_t)K_CB * 64;
  }

#pragma unroll
  for (int i = 0; i < 8; ++i) {
    int idx4 = tid + 256 * i;
    int j = idx4 >> 5;
    int d4 = (idx4 & 31) * 4;
    *(float4*)&Wl[j * 140 + d4] = *(const float4*)(W + j * 128 + d4);
  }
#pragma unroll
  for (int i = 0; i < 2; ++i) {
    int idx4 = tid + 256 * i;
    int r = idx4 >> 5;
    int d4 = (idx4 & 31) * 4;
    *(float4*)&Zl[r * 128 + d4] = *(const float4*)(src + (size_t)(n0 + r) * 128 + d4);
  }
  int j = tid & 63, g = tid >> 6;
  float bj = b[j];
  __syncthreads();

  float acc[4] = {0.f, 0.f, 0.f, 0.f};
  for (int d4 = 0; d4 < 128; d4 += 4) {
    float4 w4 = *(float4*)&Wl[j * 140 + d4];
#pragma unroll
    for (int i = 0; i < 4; ++i) {
      float4 z4 = *(float4*)&Zl[(g * 4 + i) * 128 + d4];
      acc[i] = fmaf(z4.x, w4.x, fmaf(z4.y, w4.y, fmaf(z4.z, w4.z, fmaf(z4.w, w4.w, acc[i]))));
    }
  }
#pragma unroll
  for (int i = 0; i < 4; ++i) {
    int n = n0 + g * 4 + i;
    float v = acc[i] + bj;
    __bf16 h = (__bf16)v;  float rm = v - (float)h;
    __bf16 m = (__bf16)rm; float rl = rm - (float)m;
    __bf16 l = (__bf16)rl;
    int pos = (((j >> 3) ^ (n & 7)) << 3) | (j & 7);
    size_t base = (size_t)n * 64 + pos;
    dst[base]             = h;
    dst[plane + base]     = m;
    dst[2 * plane + base] = l;
    if (do_e2) {
      float s = v * v;
#pragma unroll
      for (int off = 32; off > 0; off >>= 1) s += __shfl_xor(s, off, 64);
      if (j == 0) e2[n] = s;
    }
  }
}

// ---------------- K2: MFMA score, A-in-regs, Es double-buffered ------------
// 64 z-rows/block, K-tile 64, ONE barrier/tile; NO in-loop global stores
// (zeroing done by k_zero), so barriers drain only L2-hot Es loads issued a
// full tile earlier. 6 bf16 MFMA passes == fp32-accurate dots.
__global__ __launch_bounds__(256, 2) void k_score(
    const __bf16* __restrict__ zpl,    // [3][N_ROWS][64] swizzled
    const __bf16* __restrict__ epl,    // [3][K_CB][64] swizzled
    const float* __restrict__ e2,      // [2048]
    const float* __restrict__ emb,     // [2048][128]
    float* __restrict__ outQ,
    float* __restrict__ outOH,         // null => fallback (write cidx_g)
    int* __restrict__ cidx_g) {
  __shared__ __align__(16) __bf16 Es[2][3 * 64 * 64];   // 2 x 24 KB (planes @ 4096)
  __shared__ __align__(16) __bf16 Zs[3 * 64 * 64];      // 24 KB, prologue only
  __shared__ int cidxs[64];

  int tid = threadIdx.x, lane = tid & 63, wid = tid >> 6;
  int quad = lane >> 4, l16 = lane & 15;
  int colw = wid * 16 + l16;           // this thread's column class within a tile
  int row0 = blockIdx.x * 64;

  // prologue: stage Zs (3x8KB) and Es[0], linear 1KB copies per wave-instr
  for (int q = wid; q < 24; q += 4) {
    int p = q >> 3, within = (q & 7) * 1024;
    const char* g = (const char*)zpl + (size_t)p * ((size_t)N_ROWS * 128)
                  + (size_t)row0 * 128 + within + lane * 16;
    __builtin_amdgcn_global_load_lds((gas_p)g, (las_p)((char*)Zs + p * 8192 + within), 16, 0, 0);
  }
  for (int q = wid; q < 24; q += 4) {
    int p = q >> 3, within = (q & 7) * 1024;
    const char* g = (const char*)epl + (size_t)p * (K_CB * 128) + within + lane * 16;
    __builtin_amdgcn_global_load_lds((gas_p)g, (las_p)((char*)Es[0] + p * 8192 + within), 16, 0, 0);
  }
  float ev = e2[colw];                 // tile-0 e2, prefetched
  __syncthreads();                     // drains prologue loads

  // hoist A fragments: 24 x b128, read ONCE (loop-invariant across kt)
  bf16x8 A[2][4][3];
#pragma unroll
  for (int step = 0; step < 2; ++step)
#pragma unroll
    for (int mt = 0; mt < 4; ++mt) {
      int tr = mt * 16 + l16;
      int cph = (step * 4 + quad) ^ (l16 & 7);
      const __bf16* pa = Zs + tr * 64 + cph * 8;
      A[step][mt][0] = *(const bf16x8*)pa;
      A[step][mt][1] = *(const bf16x8*)(pa + 4096);
      A[step][mt][2] = *(const bf16x8*)(pa + 8192);
    }

  float best[16]; int bidx[16];
#pragma unroll
  for (int s = 0; s < 16; ++s) { best[s] = FLT_MAX; bidx[s] = 0; }

  for (int t = 0; t < 32; ++t) {
    int kt = t * 64;
    if (t > 0) __syncthreads();        // drains tile-t loads (issued at t-1)
    float ev_n = 0.f;
    if (t + 1 < 32) {                  // issue tile t+1 into the other buffer NOW
      __bf16* dbuf = Es[(t + 1) & 1];
      for (int q = wid; q < 24; q += 4) {
        int p = q >> 3, within = (q & 7) * 1024;
        const char* g = (const char*)epl + (size_t)p * (K_CB * 128)
                      + (size_t)(kt + 64) * 128 + within + lane * 16;
        __builtin_amdgcn_global_load_lds((gas_p)g, (las_p)((char*)dbuf + p * 8192 + within), 16, 0, 0);
      }
      ev_n = e2[kt + 64 + colw];
    }

    const __bf16* base = Es[t & 1];
    f32x4 acc[4];
#pragma unroll
    for (int mt = 0; mt < 4; ++mt) acc[mt] = (f32x4){0.f, 0.f, 0.f, 0.f};

#pragma unroll
    for (int step = 0; step < 2; ++step) {
      int cph = (step * 4 + quad) ^ (l16 & 7);
      const __bf16* pb = base + colw * 64 + cph * 8;
      bf16x8 Bh = *(const bf16x8*)pb;
      bf16x8 Bm = *(const bf16x8*)(pb + 4096);
      bf16x8 Bl = *(const bf16x8*)(pb + 8192);
#pragma unroll
      for (int mt = 0; mt < 4; ++mt) {
        f32x4 c = acc[mt];
        c = __builtin_amdgcn_mfma_f32_16x16x32_bf16(A[step][mt][2], Bh, c, 0, 0, 0); // lh
        c = __builtin_amdgcn_mfma_f32_16x16x32_bf16(A[step][mt][0], Bl, c, 0, 0, 0); // hl
        c = __builtin_amdgcn_mfma_f32_16x16x32_bf16(A[step][mt][1], Bm, c, 0, 0, 0); // mm
        c = __builtin_amdgcn_mfma_f32_16x16x32_bf16(A[step][mt][1], Bh, c, 0, 0, 0); // mh
        c = __builtin_amdgcn_mfma_f32_16x16x32_bf16(A[step][mt][0], Bm, c, 0, 0, 0); // hm
        c = __builtin_amdgcn_mfma_f32_16x16x32_bf16(A[step][mt][0], Bh, c, 0, 0, 0); // hh
        acc[mt] = c;
      }
    }

    int col = kt + colw;               // ascending kt + strict < => earliest index
#pragma unroll
    for (int mt = 0; mt < 4; ++mt)
#pragma unroll
      for (int r = 0; r < 4; ++r) {
        float s = fmaf(-2.0f, acc[mt][r], ev);
        int slot = mt * 4 + r;
        if (s < best[slot]) { best[slot] = s; bidx[slot] = col; }
      }
    ev = ev_n;
  }

  // 2-stage argmin reduce: 64 col-classes per row, conflict-free layouts
  __syncthreads();
  float* redm = (float*)Es;                    // [64 slots][65]
  int*   redi = (int*)(redm + 64 * 65);        // [64 slots][65]
#pragma unroll
  for (int mt = 0; mt < 4; ++mt)
#pragma unroll
    for (int r = 0; r < 4; ++r) {
      int row = mt * 16 + quad * 4 + r;        // C-layout: row = quad*4 + reg
      redm[colw * 65 + row] = best[mt * 4 + r];
      redi[colw * 65 + row] = bidx[mt * 4 + r];
    }
  __syncthreads();
  float* rm2 = (float*)Zs;                     // [64][4]
  int*   ri2 = (int*)(rm2 + 256);
  {
    int row = tid & 63, qq = tid >> 6;         // each thread reduces 16 slots
    float m = redm[(qq * 16) * 65 + row]; int mi = redi[(qq * 16) * 65 + row];
#pragma unroll
    for (int s = 1; s < 16; ++s) {
      float v = redm[(qq * 16 + s) * 65 + row]; int vi = redi[(qq * 16 + s) * 65 + row];
      if (v < m || (v == m && vi < mi)) { m = v; mi = vi; }
    }
    rm2[row * 4 + qq] = m; ri2[row * 4 + qq] = mi;
  }
  __syncthreads();
  if (tid < 64) {
    float m = rm2[tid * 4]; int mi = ri2[tid * 4];
#pragma unroll
    for (int s = 1; s < 4; ++s) {
      float v = rm2[tid * 4 + s]; int vi = ri2[tid * 4 + s];
      if (v < m || (v == m && vi < mi)) { m = v; mi = vi; }
    }
    cidxs[tid] = mi;
  }
  __syncthreads();

  if (outOH) {
    // zeros were written by k_zero (stream-ordered before this kernel)
    if (tid < 64) outOH[(size_t)(row0 + tid) * K_CB + cidxs[tid]] = 1.0f;
  } else {
    if (tid < 64) cidx_g[row0 + tid] = cidxs[tid];
  }

  // quantized gather (emb is L2-hot, 1 MB)
#pragma unroll
  for (int i = 0; i < 8; ++i) {
    int idx = tid + 256 * i;
    int r = idx >> 5, c = (idx & 31) * 4;
    *(float4*)(outQ + (size_t)(row0 + r) * D_IN + c) =
        *(const float4*)(emb + (size_t)cidxs[r] * D_IN + c);
  }
}

// ---------------- K3: fallback epilogue (zero one_hot + scatter) -----------
__global__ void k_epilogue(const int* __restrict__ cidx_g, float* __restrict__ outOH) {
  int tid  = threadIdx.x;
  int row0 = blockIdx.x * 64;
  float4 zz4 = make_float4(0.f, 0.f, 0.f, 0.f);
  for (int r = 0; r < 64; ++r) {
    float4* dst = (float4*)(outOH + (size_t)(row0 + r) * K_CB);
    dst[tid]       = zz4;
    dst[tid + 256] = zz4;
  }
  __syncthreads();
  if (tid < 64) {
    int r = row0 + tid;
    outOH[(size_t)r * K_CB + cidx_g[r]] = 1.0f;
  }
}

extern "C" void kernel_launch(void* const* d_in, const int* in_sizes, int n_in,
                              void* d_out, int out_size, void* d_ws, size_t ws_size,
                              hipStream_t stream) {
  (void)in_sizes; (void)n_in; (void)out_size;
  const float* Z   = (const float*)d_in[0];
  const float* W   = (const float*)d_in[1];
  const float* b   = (const float*)d_in[2];
  const float* emb = (const float*)d_in[3];
  float* outQ  = (float*)d_out;
  float* outOH = (float*)d_out + (size_t)N_ROWS * D_IN;

  // ws layout (bytes): epl 786432 | e2 8192 | (zpl 25165824  OR  cidx 262144)
  char* wsb = (char*)d_ws;
  __bf16* epl = (__bf16*)wsb;
  float*  e2  = (float*)(wsb + 786432);
  const size_t need_primary = 786432 + 8192 + (size_t)3 * N_ROWS * 64 * 2;

  if (ws_size >= need_primary) {
    __bf16* zpl = (__bf16*)(wsb + 794624);
    k_zero<<<8192, 256, 0, stream>>>((float4*)outOH);          // 512 MB @ write BW
    k_project<<<4224, 256, 0, stream>>>(Z, emb, W, b, zpl, epl, e2);
    k_score<<<1024, 256, 0, stream>>>(zpl, epl, e2, emb, outQ, outOH, nullptr);
  } else {
    int*    cidx_g = (int*)(wsb + 794624);
    __bf16* zpl    = (__bf16*)outOH;   // one_hot region doubles as scratch
    k_project<<<4224, 256, 0, stream>>>(Z, emb, W, b, zpl, epl, e2);
    k_score<<<1024, 256, 0, stream>>>(zpl, epl, e2, emb, outQ, nullptr, cidx_g);
    k_epilogue<<<1024, 256, 0, stream>>>(cidx_g, outOH);
  }
}

// Round 7
// 745.301 us; speedup vs baseline: 1.0407x; 1.0152x over previous
//
#include <hip/hip_runtime.h>
#include <float.h>

#define N_ROWS 65536
#define D_IN   128
#define DH     64
#define K_CB   2048

typedef const __attribute__((address_space(1))) void* gas_p;
typedef __attribute__((address_space(3))) void* las_p;
typedef __bf16 bf16x8 __attribute__((ext_vector_type(8)));
typedef float  f32x4  __attribute__((ext_vector_type(4)));

// swizzle: logical 16B-chunk c of row n stored at c ^ ((n ^ (n>>3)) & 7)
// -> frag ds_reads are exactly 2-way (free) for both A and B access patterns.
__device__ __forceinline__ int swz(int n) { return (n ^ (n >> 3)) & 7; }

// ---------------- K1: project 128 -> 64, emit 3-plane bf16 split -----------
// z = zh + zm + zl exactly (24-bit mantissa). blocks 0..4095: z rows;
// 4096..4223: emb rows + e2 (exact fp32 ||e_||^2).
__global__ __launch_bounds__(256) void k_project(
    const float* __restrict__ Z, const float* __restrict__ emb,
    const float* __restrict__ W, const float* __restrict__ b,
    __bf16* __restrict__ zpl,   // [3][N_ROWS][64]
    __bf16* __restrict__ epl,   // [3][K_CB][64]
    float* __restrict__ e2) {
  __shared__ __align__(16) float Wl[64 * 140];
  __shared__ __align__(16) float Zl[16 * 128];
  int tid = threadIdx.x;
  const float* src; __bf16* dst; int n0; bool do_e2; size_t plane;
  if ((int)blockIdx.x < 4096) {
    src = Z;   dst = zpl; n0 = blockIdx.x * 16;          do_e2 = false; plane = (size_t)N_ROWS * 64;
  } else {
    src = emb; dst = epl; n0 = (blockIdx.x - 4096) * 16; do_e2 = true;  plane = (size_t)K_CB * 64;
  }

#pragma unroll
  for (int i = 0; i < 8; ++i) {
    int idx4 = tid + 256 * i;
    int j = idx4 >> 5;
    int d4 = (idx4 & 31) * 4;
    *(float4*)&Wl[j * 140 + d4] = *(const float4*)(W + j * 128 + d4);
  }
#pragma unroll
  for (int i = 0; i < 2; ++i) {
    int idx4 = tid + 256 * i;
    int r = idx4 >> 5;
    int d4 = (idx4 & 31) * 4;
    *(float4*)&Zl[r * 128 + d4] = *(const float4*)(src + (size_t)(n0 + r) * 128 + d4);
  }
  int j = tid & 63, g = tid >> 6;
  float bj = b[j];
  __syncthreads();

  float acc[4] = {0.f, 0.f, 0.f, 0.f};
  for (int d4 = 0; d4 < 128; d4 += 4) {
    float4 w4 = *(float4*)&Wl[j * 140 + d4];
#pragma unroll
    for (int i = 0; i < 4; ++i) {
      float4 z4 = *(float4*)&Zl[(g * 4 + i) * 128 + d4];   // wave-uniform broadcast
      acc[i] = fmaf(z4.x, w4.x, fmaf(z4.y, w4.y, fmaf(z4.z, w4.z, fmaf(z4.w, w4.w, acc[i]))));
    }
  }
#pragma unroll
  for (int i = 0; i < 4; ++i) {
    int n = n0 + g * 4 + i;
    float v = acc[i] + bj;
    __bf16 h = (__bf16)v;  float rm = v - (float)h;
    __bf16 m = (__bf16)rm; float rl = rm - (float)m;
    __bf16 l = (__bf16)rl;
    int pos = (((j >> 3) ^ swz(n)) << 3) | (j & 7);
    size_t base = (size_t)n * 64 + pos;
    dst[base]             = h;
    dst[plane + base]     = m;
    dst[2 * plane + base] = l;
    if (do_e2) {
      float s = v * v;
#pragma unroll
      for (int off = 32; off > 0; off >>= 1) s += __shfl_xor(s, off, 64);
      if (j == 0) e2[n] = s;
    }
  }
}

// ---------------- K2: MFMA score -> cidx ONLY ------------------------------
// 64 z-rows/block, K-tile 64, one barrier/tile, Es double-buffered, A in regs.
// 6 bf16 MFMA passes (hh,hm,mh,mm,hl,lh) == fp32-accurate dots. No big stores.
__global__ __launch_bounds__(256, 2) void k_score(
    const __bf16* __restrict__ zpl,    // [3][N_ROWS][64] swizzled
    const __bf16* __restrict__ epl,    // [3][K_CB][64] swizzled
    const float* __restrict__ e2,      // [2048]
    int* __restrict__ cidx_g) {
  __shared__ __align__(16) __bf16 Es[2][3 * 64 * 64];   // 2 x 24 KB
  __shared__ __align__(16) __bf16 Zs[3 * 64 * 64];      // 24 KB, prologue only
  int tid = threadIdx.x, lane = tid & 63, wid = tid >> 6;
  int quad = lane >> 4, l16 = lane & 15;
  int colw = wid * 16 + l16;
  int row0 = blockIdx.x * 64;

  for (int q = wid; q < 24; q += 4) {
    int p = q >> 3, within = (q & 7) * 1024;
    const char* g = (const char*)zpl + (size_t)p * ((size_t)N_ROWS * 128)
                  + (size_t)row0 * 128 + within + lane * 16;
    __builtin_amdgcn_global_load_lds((gas_p)g, (las_p)((char*)Zs + p * 8192 + within), 16, 0, 0);
  }
  for (int q = wid; q < 24; q += 4) {
    int p = q >> 3, within = (q & 7) * 1024;
    const char* g = (const char*)epl + (size_t)p * (K_CB * 128) + within + lane * 16;
    __builtin_amdgcn_global_load_lds((gas_p)g, (las_p)((char*)Es[0] + p * 8192 + within), 16, 0, 0);
  }
  float ev = e2[colw];
  __syncthreads();

  bf16x8 A[2][4][3];
#pragma unroll
  for (int step = 0; step < 2; ++step)
#pragma unroll
    for (int mt = 0; mt < 4; ++mt) {
      int tr = mt * 16 + l16;
      int cph = (step * 4 + quad) ^ swz(tr);
      const __bf16* pa = Zs + tr * 64 + cph * 8;
      A[step][mt][0] = *(const bf16x8*)pa;
      A[step][mt][1] = *(const bf16x8*)(pa + 4096);
      A[step][mt][2] = *(const bf16x8*)(pa + 8192);
    }

  float best[16]; int bidx[16];
#pragma unroll
  for (int s = 0; s < 16; ++s) { best[s] = FLT_MAX; bidx[s] = 0; }

  for (int t = 0; t < 32; ++t) {
    int kt = t * 64;
    if (t > 0) __syncthreads();        // drains tile-t loads (issued at t-1)
    float ev_n = 0.f;
    if (t + 1 < 32) {
      __bf16* dbuf = Es[(t + 1) & 1];
      for (int q = wid; q < 24; q += 4) {
        int p = q >> 3, within = (q & 7) * 1024;
        const char* g = (const char*)epl + (size_t)p * (K_CB * 128)
                      + (size_t)(kt + 64) * 128 + within + lane * 16;
        __builtin_amdgcn_global_load_lds((gas_p)g, (las_p)((char*)dbuf + p * 8192 + within), 16, 0, 0);
      }
      ev_n = e2[kt + 64 + colw];
    }

    const __bf16* base = Es[t & 1];
    f32x4 acc[4];
#pragma unroll
    for (int mt = 0; mt < 4; ++mt) acc[mt] = (f32x4){0.f, 0.f, 0.f, 0.f};

#pragma unroll
    for (int step = 0; step < 2; ++step) {
      int cph = (step * 4 + quad) ^ swz(colw);
      const __bf16* pb = base + colw * 64 + cph * 8;
      bf16x8 Bh = *(const bf16x8*)pb;
      bf16x8 Bm = *(const bf16x8*)(pb + 4096);
      bf16x8 Bl = *(const bf16x8*)(pb + 8192);
#pragma unroll
      for (int mt = 0; mt < 4; ++mt) {
        f32x4 c = acc[mt];
        c = __builtin_amdgcn_mfma_f32_16x16x32_bf16(A[step][mt][2], Bh, c, 0, 0, 0); // lh
        c = __builtin_amdgcn_mfma_f32_16x16x32_bf16(A[step][mt][0], Bl, c, 0, 0, 0); // hl
        c = __builtin_amdgcn_mfma_f32_16x16x32_bf16(A[step][mt][1], Bm, c, 0, 0, 0); // mm
        c = __builtin_amdgcn_mfma_f32_16x16x32_bf16(A[step][mt][1], Bh, c, 0, 0, 0); // mh
        c = __builtin_amdgcn_mfma_f32_16x16x32_bf16(A[step][mt][0], Bm, c, 0, 0, 0); // hm
        c = __builtin_amdgcn_mfma_f32_16x16x32_bf16(A[step][mt][0], Bh, c, 0, 0, 0); // hh
        acc[mt] = c;
      }
    }

    int col = kt + colw;               // ascending kt + strict < => earliest index
#pragma unroll
    for (int mt = 0; mt < 4; ++mt)
#pragma unroll
      for (int r = 0; r < 4; ++r) {
        float s = fmaf(-2.0f, acc[mt][r], ev);
        int slot = mt * 4 + r;
        if (s < best[slot]) { best[slot] = s; bidx[slot] = col; }
      }
    ev = ev_n;
  }

  // 2-stage argmin reduce, conflict-free layouts
  __syncthreads();
  float* redm = (float*)Es;                    // [64 col-classes][65]
  int*   redi = (int*)(redm + 64 * 65);
#pragma unroll
  for (int mt = 0; mt < 4; ++mt)
#pragma unroll
    for (int r = 0; r < 4; ++r) {
      int row = mt * 16 + quad * 4 + r;        // C-layout: row = quad*4 + reg
      redm[colw * 65 + row] = best[mt * 4 + r];
      redi[colw * 65 + row] = bidx[mt * 4 + r];
    }
  __syncthreads();
  float* rm2 = (float*)Zs;                     // [64][4]
  int*   ri2 = (int*)(rm2 + 256);
  {
    int row = tid & 63, qq = tid >> 6;
    float m = redm[(qq * 16) * 65 + row]; int mi = redi[(qq * 16) * 65 + row];
#pragma unroll
    for (int s = 1; s < 16; ++s) {
      float v = redm[(qq * 16 + s) * 65 + row]; int vi = redi[(qq * 16 + s) * 65 + row];
      if (v < m || (v == m && vi < mi)) { m = v; mi = vi; }
    }
    rm2[row * 4 + qq] = m; ri2[row * 4 + qq] = mi;
  }
  __syncthreads();
  if (tid < 64) {
    float m = rm2[tid * 4]; int mi = ri2[tid * 4];
#pragma unroll
    for (int s = 1; s < 4; ++s) {
      float v = rm2[tid * 4 + s]; int vi = ri2[tid * 4 + s];
      if (v < m || (v == m && vi < mi)) { m = v; mi = vi; }
    }
    cidx_g[row0 + tid] = mi;
  }
}

// ---------------- K3: stream outputs — every line written ONCE -------------
// 32 rows/block: one_hot row = (c == cidx[r]); quantized row = emb[cidx[r]].
__global__ __launch_bounds__(256) void k_out(
    const int* __restrict__ cidx_g, const float* __restrict__ emb,
    float* __restrict__ outQ, float* __restrict__ outOH) {
  __shared__ int ci[32];
  int tid = threadIdx.x;
  int row0 = blockIdx.x * 32;
  if (tid < 32) ci[tid] = cidx_g[row0 + tid];
  __syncthreads();
  // quantized: 32 rows x 32 float4 (emb 1 MB, L2-hot)
#pragma unroll
  for (int i = 0; i < 4; ++i) {
    int idx = tid + 256 * i;
    int r = idx >> 5, c = (idx & 31) * 4;
    *(float4*)(outQ + (size_t)(row0 + r) * D_IN + c) =
        *(const float4*)(emb + (size_t)ci[r] * D_IN + c);
  }
  // one_hot: full-line coalesced stores, value = select
  for (int r = 0; r < 32; ++r) {
    int col = ci[r];
    float* dst = outOH + (size_t)(row0 + r) * K_CB;
#pragma unroll
    for (int i = 0; i < 2; ++i) {
      int c4 = (tid + 256 * i) * 4;
      float4 v;
      v.x = (c4     == col) ? 1.f : 0.f;
      v.y = (c4 + 1 == col) ? 1.f : 0.f;
      v.z = (c4 + 2 == col) ? 1.f : 0.f;
      v.w = (c4 + 3 == col) ? 1.f : 0.f;
      *(float4*)(dst + c4) = v;
    }
  }
}

extern "C" void kernel_launch(void* const* d_in, const int* in_sizes, int n_in,
                              void* d_out, int out_size, void* d_ws, size_t ws_size,
                              hipStream_t stream) {
  (void)in_sizes; (void)n_in; (void)out_size;
  const float* Z   = (const float*)d_in[0];
  const float* W   = (const float*)d_in[1];
  const float* b   = (const float*)d_in[2];
  const float* emb = (const float*)d_in[3];
  float* outQ  = (float*)d_out;
  float* outOH = (float*)d_out + (size_t)N_ROWS * D_IN;

  // ws layout (bytes): epl 786432 | e2 8192 | cidx 262144 | zpl 25165824
  char* wsb = (char*)d_ws;
  __bf16* epl    = (__bf16*)wsb;
  float*  e2     = (float*)(wsb + 786432);
  int*    cidx_g = (int*)(wsb + 794624);
  const size_t need_primary = 786432 + 8192 + 262144 + (size_t)3 * N_ROWS * 64 * 2;

  __bf16* zpl;
  if (ws_size >= need_primary) {
    zpl = (__bf16*)(wsb + 1056768);
  } else {
    zpl = (__bf16*)outOH;   // one_hot region as scratch; k_out overwrites it after
  }
  k_project<<<4224, 256, 0, stream>>>(Z, emb, W, b, zpl, epl, e2);
  k_score<<<1024, 256, 0, stream>>>(zpl, epl, e2, cidx_g);
  k_out<<<2048, 256, 0, stream>>>(cidx_g, emb, outQ, outOH);
}

// Round 8
// 715.791 us; speedup vs baseline: 1.0836x; 1.0412x over previous
//
#include <hip/hip_runtime.h>
#include <float.h>

#define N_ROWS 65536
#define D_IN   128
#define DH     64
#define K_CB   2048

typedef const __attribute__((address_space(1))) void* gas_p;
typedef __attribute__((address_space(3))) void* las_p;
typedef __bf16 bf16x8 __attribute__((ext_vector_type(8)));
typedef float  f32x4  __attribute__((ext_vector_type(4)));

// swizzle: logical 16B-chunk c of row n stored at c ^ ((n ^ (n>>3)) & 7)
__device__ __forceinline__ int swz(int n) { return (n ^ (n >> 3)) & 7; }

// ---------------- K1: project 128 -> 64, emit 3-plane bf16 split -----------
// z = zh + zm + zl exactly (24-bit mantissa). blocks 0..4095: z rows;
// 4096..4223: emb rows + e2 (exact fp32 ||e_||^2).
__global__ __launch_bounds__(256) void k_project(
    const float* __restrict__ Z, const float* __restrict__ emb,
    const float* __restrict__ W, const float* __restrict__ b,
    __bf16* __restrict__ zpl,   // [3][N_ROWS][64]
    __bf16* __restrict__ epl,   // [3][K_CB][64]
    float* __restrict__ e2) {
  __shared__ __align__(16) float Wl[64 * 140];
  __shared__ __align__(16) float Zl[16 * 128];
  int tid = threadIdx.x;
  const float* src; __bf16* dst; int n0; bool do_e2; size_t plane;
  if ((int)blockIdx.x < 4096) {
    src = Z;   dst = zpl; n0 = blockIdx.x * 16;          do_e2 = false; plane = (size_t)N_ROWS * 64;
  } else {
    src = emb; dst = epl; n0 = (blockIdx.x - 4096) * 16; do_e2 = true;  plane = (size_t)K_CB * 64;
  }

#pragma unroll
  for (int i = 0; i < 8; ++i) {
    int idx4 = tid + 256 * i;
    int j = idx4 >> 5;
    int d4 = (idx4 & 31) * 4;
    *(float4*)&Wl[j * 140 + d4] = *(const float4*)(W + j * 128 + d4);
  }
#pragma unroll
  for (int i = 0; i < 2; ++i) {
    int idx4 = tid + 256 * i;
    int r = idx4 >> 5;
    int d4 = (idx4 & 31) * 4;
    *(float4*)&Zl[r * 128 + d4] = *(const float4*)(src + (size_t)(n0 + r) * 128 + d4);
  }
  int j = tid & 63, g = tid >> 6;
  float bj = b[j];
  __syncthreads();

  float acc[4] = {0.f, 0.f, 0.f, 0.f};
  for (int d4 = 0; d4 < 128; d4 += 4) {
    float4 w4 = *(float4*)&Wl[j * 140 + d4];
#pragma unroll
    for (int i = 0; i < 4; ++i) {
      float4 z4 = *(float4*)&Zl[(g * 4 + i) * 128 + d4];   // wave-uniform broadcast
      acc[i] = fmaf(z4.x, w4.x, fmaf(z4.y, w4.y, fmaf(z4.z, w4.z, fmaf(z4.w, w4.w, acc[i]))));
    }
  }
#pragma unroll
  for (int i = 0; i < 4; ++i) {
    int n = n0 + g * 4 + i;
    float v = acc[i] + bj;
    __bf16 h = (__bf16)v;  float rm = v - (float)h;
    __bf16 m = (__bf16)rm; float rl = rm - (float)m;
    __bf16 l = (__bf16)rl;
    int pos = (((j >> 3) ^ swz(n)) << 3) | (j & 7);
    size_t base = (size_t)n * 64 + pos;
    dst[base]             = h;
    dst[plane + base]     = m;
    dst[2 * plane + base] = l;
    if (do_e2) {
      float s = v * v;
#pragma unroll
      for (int off = 32; off > 0; off >>= 1) s += __shfl_xor(s, off, 64);
      if (j == 0) e2[n] = s;
    }
  }
}

// ---------------- K2: MFMA score, BARRIER-FREE K-loop ----------------------
// 64 z-rows/block. A hoisted to regs (prologue). B-frags loaded DIRECTLY from
// global (L2-hot epl) into VGPRs, reg ping-pong prefetch. No LDS / syncthreads
// in the stream loop. 6 bf16 MFMA passes == fp32-accurate dots.
__global__ __launch_bounds__(256, 2) void k_score(
    const __bf16* __restrict__ zpl,    // [3][N_ROWS][64] swizzled
    const __bf16* __restrict__ epl,    // [3][K_CB][64] swizzled
    const float* __restrict__ e2,      // [2048]
    int* __restrict__ cidx_g) {
  __shared__ __align__(16) char smem[35328];   // Zs(24KB) then reduce scratch
  __bf16* Zs = (__bf16*)smem;

  int tid = threadIdx.x, lane = tid & 63, wid = tid >> 6;
  int quad = lane >> 4, l16 = lane & 15;
  int colw = wid * 16 + l16;
  int row0 = blockIdx.x * 64;

  // prologue: stage Zs tile (3 planes x 8KB), linear copies
  for (int q = wid; q < 24; q += 4) {
    int p = q >> 3, within = (q & 7) * 1024;
    const char* g = (const char*)zpl + (size_t)p * ((size_t)N_ROWS * 128)
                  + (size_t)row0 * 128 + within + lane * 16;
    __builtin_amdgcn_global_load_lds((gas_p)g, (las_p)(smem + p * 8192 + within), 16, 0, 0);
  }
  __syncthreads();

  // hoist A fragments: 24 x b128 from LDS, once
  bf16x8 A[2][4][3];
#pragma unroll
  for (int step = 0; step < 2; ++step)
#pragma unroll
    for (int mt = 0; mt < 4; ++mt) {
      int tr = mt * 16 + l16;
      int cph = (step * 4 + quad) ^ swz(tr);
      const __bf16* pa = Zs + tr * 64 + cph * 8;
      A[step][mt][0] = *(const bf16x8*)pa;
      A[step][mt][1] = *(const bf16x8*)(pa + 4096);
      A[step][mt][2] = *(const bf16x8*)(pa + 8192);
    }

  float best[16]; int bidx[16];
#pragma unroll
  for (int s = 0; s < 16; ++s) { best[s] = FLT_MAX; bidx[s] = 0; }

  // B-frag base addressing (global, per-lane). swz(kt+colw)==swz(colw) since
  // kt is a multiple of 64. Plane stride = K_CB*64 = 131072 elems.
  int sz = swz(colw);
  const __bf16* bbase = epl + (size_t)colw * 64;
  int off0 = ((0 * 4 + quad) ^ sz) * 8;
  int off1 = ((1 * 4 + quad) ^ sz) * 8;

  bf16x8 B0[6], B1[6]; float ev0, ev1;
  auto loadB = [&](bf16x8* B, float& ev, int kt) {
    const __bf16* bb = bbase + (size_t)kt * 64;
    B[0] = *(const bf16x8*)(bb + off0);            // step0 hi
    B[1] = *(const bf16x8*)(bb + 131072 + off0);   // step0 mid
    B[2] = *(const bf16x8*)(bb + 262144 + off0);   // step0 lo
    B[3] = *(const bf16x8*)(bb + off1);            // step1 hi
    B[4] = *(const bf16x8*)(bb + 131072 + off1);   // step1 mid
    B[5] = *(const bf16x8*)(bb + 262144 + off1);   // step1 lo
    ev = e2[kt + colw];
  };
  auto compute = [&](const bf16x8* B, float ev, int kt) {
    f32x4 acc[4];
#pragma unroll
    for (int mt = 0; mt < 4; ++mt) acc[mt] = (f32x4){0.f, 0.f, 0.f, 0.f};
#pragma unroll
    for (int s = 0; s < 2; ++s)
#pragma unroll
      for (int mt = 0; mt < 4; ++mt) {
        f32x4 c = acc[mt];
        c = __builtin_amdgcn_mfma_f32_16x16x32_bf16(A[s][mt][2], B[s * 3 + 0], c, 0, 0, 0); // lh
        c = __builtin_amdgcn_mfma_f32_16x16x32_bf16(A[s][mt][0], B[s * 3 + 2], c, 0, 0, 0); // hl
        c = __builtin_amdgcn_mfma_f32_16x16x32_bf16(A[s][mt][1], B[s * 3 + 1], c, 0, 0, 0); // mm
        c = __builtin_amdgcn_mfma_f32_16x16x32_bf16(A[s][mt][1], B[s * 3 + 0], c, 0, 0, 0); // mh
        c = __builtin_amdgcn_mfma_f32_16x16x32_bf16(A[s][mt][0], B[s * 3 + 1], c, 0, 0, 0); // hm
        c = __builtin_amdgcn_mfma_f32_16x16x32_bf16(A[s][mt][0], B[s * 3 + 0], c, 0, 0, 0); // hh
        acc[mt] = c;
      }
    int col = kt + colw;               // ascending kt + strict < => earliest index
#pragma unroll
    for (int mt = 0; mt < 4; ++mt)
#pragma unroll
      for (int r = 0; r < 4; ++r) {
        float s = fmaf(-2.0f, acc[mt][r], ev);
        int slot = mt * 4 + r;
        if (s < best[slot]) { best[slot] = s; bidx[slot] = col; }
      }
  };

  loadB(B0, ev0, 0);
  for (int t = 0; t < 32; t += 2) {
    loadB(B1, ev1, (t + 1) * 64);                  // prefetch t+1 during compute t
    compute(B0, ev0, t * 64);
    int kt2 = (t + 2 < 32) ? (t + 2) * 64 : 0;     // clamped (junk unused)
    loadB(B0, ev0, kt2);                           // prefetch t+2 during compute t+1
    compute(B1, ev1, (t + 1) * 64);
  }

  // 2-stage argmin reduce (smem reused; all Zs reads done before this barrier)
  __syncthreads();
  float* redm = (float*)smem;                       // [64 col-classes][65]
  int*   redi = (int*)(smem + 16640);
#pragma unroll
  for (int mt = 0; mt < 4; ++mt)
#pragma unroll
    for (int r = 0; r < 4; ++r) {
      int row = mt * 16 + quad * 4 + r;             // C-layout: row = quad*4 + reg
      redm[colw * 65 + row] = best[mt * 4 + r];
      redi[colw * 65 + row] = bidx[mt * 4 + r];
    }
  __syncthreads();
  float* rm2 = (float*)(smem + 33280);              // [64][4]
  int*   ri2 = (int*)(smem + 33280 + 1024);
  {
    int row = tid & 63, qq = tid >> 6;
    float m = redm[(qq * 16) * 65 + row]; int mi = redi[(qq * 16) * 65 + row];
#pragma unroll
    for (int s = 1; s < 16; ++s) {
      float v = redm[(qq * 16 + s) * 65 + row]; int vi = redi[(qq * 16 + s) * 65 + row];
      if (v < m || (v == m && vi < mi)) { m = v; mi = vi; }
    }
    rm2[row * 4 + qq] = m; ri2[row * 4 + qq] = mi;
  }
  __syncthreads();
  if (tid < 64) {
    float m = rm2[tid * 4]; int mi = ri2[tid * 4];
#pragma unroll
    for (int s = 1; s < 4; ++s) {
      float v = rm2[tid * 4 + s]; int vi = ri2[tid * 4 + s];
      if (v < m || (v == m && vi < mi)) { m = v; mi = vi; }
    }
    cidx_g[row0 + tid] = mi;
  }
}

// ---------------- K3: stream outputs — every line written ONCE -------------
__global__ __launch_bounds__(256) void k_out(
    const int* __restrict__ cidx_g, const float* __restrict__ emb,
    float* __restrict__ outQ, float* __restrict__ outOH) {
  __shared__ int ci[32];
  int tid = threadIdx.x;
  int row0 = blockIdx.x * 32;
  if (tid < 32) ci[tid] = cidx_g[row0 + tid];
  __syncthreads();
#pragma unroll
  for (int i = 0; i < 4; ++i) {
    int idx = tid + 256 * i;
    int r = idx >> 5, c = (idx & 31) * 4;
    *(float4*)(outQ + (size_t)(row0 + r) * D_IN + c) =
        *(const float4*)(emb + (size_t)ci[r] * D_IN + c);
  }
  for (int r = 0; r < 32; ++r) {
    int col = ci[r];
    float* dst = outOH + (size_t)(row0 + r) * K_CB;
#pragma unroll
    for (int i = 0; i < 2; ++i) {
      int c4 = (tid + 256 * i) * 4;
      float4 v;
      v.x = (c4     == col) ? 1.f : 0.f;
      v.y = (c4 + 1 == col) ? 1.f : 0.f;
      v.z = (c4 + 2 == col) ? 1.f : 0.f;
      v.w = (c4 + 3 == col) ? 1.f : 0.f;
      *(float4*)(dst + c4) = v;
    }
  }
}

extern "C" void kernel_launch(void* const* d_in, const int* in_sizes, int n_in,
                              void* d_out, int out_size, void* d_ws, size_t ws_size,
                              hipStream_t stream) {
  (void)in_sizes; (void)n_in; (void)out_size;
  const float* Z   = (const float*)d_in[0];
  const float* W   = (const float*)d_in[1];
  const float* b   = (const float*)d_in[2];
  const float* emb = (const float*)d_in[3];
  float* outQ  = (float*)d_out;
  float* outOH = (float*)d_out + (size_t)N_ROWS * D_IN;

  // ws layout (bytes): epl 786432 | e2 8192 | cidx 262144 | zpl 25165824
  char* wsb = (char*)d_ws;
  __bf16* epl    = (__bf16*)wsb;
  float*  e2     = (float*)(wsb + 786432);
  int*    cidx_g = (int*)(wsb + 794624);
  const size_t need_primary = 786432 + 8192 + 262144 + (size_t)3 * N_ROWS * 64 * 2;

  __bf16* zpl;
  if (ws_size >= need_primary) {
    zpl = (__bf16*)(wsb + 1056768);
  } else {
    zpl = (__bf16*)outOH;   // one_hot region as scratch; k_out overwrites it after
  }
  k_project<<<4224, 256, 0, stream>>>(Z, emb, W, b, zpl, epl, e2);
  k_score<<<1024, 256, 0, stream>>>(zpl, epl, e2, cidx_g);
  k_out<<<2048, 256, 0, stream>>>(cidx_g, emb, outQ, outOH);
}